// Round 1
// baseline (318.730 us; speedup 1.0000x reference)
//
#include <hip/hip_runtime.h>
#include <hip/hip_bf16.h>
#include <hip/hip_fp16.h>
#include <math.h>

#define SSEPS 1e-24f
#define NPB 256           // nodes per bucket
#define NPB_SHIFT 8
#define SRC_BITS 17       // N = 131072 = 2^17
#define SRC_MASK ((1 << SRC_BITS) - 1)
#define NB 512            // buckets (N / NPB)
#define CAP_B 8832        // padded per-bucket region (mean 8192 + 7 sigma)
#define SC_EDGES 8192     // edges per bucket_scatter block
#define SCB 512           // bucket count in scatter LDS
#define SC_T 512          // bucket_scatter threads
#define CSR_T 512         // csr_build threads
#define DBINS 256         // degree bins for node sort

union QRowU2 { int4 v; _Float16 h[8]; };

// Node record: 32 B = 8 ints = fp16[16] RAW feature row. With 2 lanes/node each
// lane gathers one int4 (16 B); norms/projections recomputed in-register.

// ---------------- utility kernels ----------------

__global__ void init_gcursor(int* g, int* hist) {
    int i = threadIdx.x;
    if (i < NB) g[i] = i * CAP_B;
    if (i < DBINS) hist[i] = 0;
}

__global__ void init_out(float* out, const float* gb, int G) {
    int g = blockIdx.x * blockDim.x + threadIdx.x;
    if (g < G) out[g] = gb[0];
}

// v[c] = sum_j gather_w[j] * lin2_w[j][c]  (c<16);  v[16] = gather_w . lin2_b
__global__ void compute_v(const float* l2w, const float* l2b, const float* gw,
                          float* vbuf) {
    int t = threadIdx.x;
    if (t < 16) {
        float a = 0.f;
        for (int j = 0; j < 64; ++j) a = fmaf(gw[j], l2w[j * 16 + t], a);
        vbuf[t] = a;
    } else if (t == 16) {
        float a = 0.f;
        for (int j = 0; j < 64; ++j) a = fmaf(gw[j], l2b[j], a);
        vbuf[16] = a;
    }
}

// ---------------- lin1 + relu -> raw fp16 rows (32 B/node) ----------------
__global__ void lin1_relu(const float* __restrict__ x,
                          const float* __restrict__ W1,
                          const float* __restrict__ b1,
                          int* __restrict__ rec1, int N, int D) {
    __shared__ float Ws[16 * 75];
    __shared__ float Bs[16];
    for (int i = threadIdx.x; i < 16 * D; i += blockDim.x) Ws[i] = W1[i];
    if (threadIdx.x < 16) Bs[threadIdx.x] = b1[threadIdx.x];
    __syncthreads();

    int node = blockIdx.x * (blockDim.x >> 4) + (threadIdx.x >> 4);
    int c = threadIdx.x & 15;
    if (node >= N) return;

    const float* xr = x + (size_t)node * D;
    float acc = Bs[c];
    for (int k = 0; k < D; ++k) acc = fmaf(xr[k], Ws[c * D + k], acc);
    float h = fmaxf(acc, 0.f);

    float hn = __shfl_xor(h, 1);
    if (!(c & 1)) {
        union { _Float16 hh[2]; int i; } u;
        u.hh[0] = (_Float16)h;
        u.hh[1] = (_Float16)hn;
        rec1[8 * node + (c >> 1)] = u.i;
    }
}

// ---------------- bucketed CSR build (padded regions, no global scan) ----------

__global__ __launch_bounds__(SC_T) void bucket_scatter(
    const int* __restrict__ src, const int* __restrict__ dst,
    int E, int* __restrict__ gcursor, int* __restrict__ packed) {
    __shared__ int lout[SC_EDGES];  // 32 KB
    __shared__ int h[SCB];
    __shared__ int s[SCB];
    __shared__ int delta[SCB];
    int t = threadIdx.x;
    int base = blockIdx.x * SC_EDGES;
    int cnt = E - base;
    if (cnt > SC_EDGES) cnt = SC_EDGES;

    if (t < SCB) h[t] = 0;
    __syncthreads();
    for (int i = t; i < cnt; i += SC_T)
        atomicAdd(&h[dst[base + i] >> NPB_SHIFT], 1);
    __syncthreads();
    // Hillis-Steele inclusive scan, 1 entry/thread (SCB == SC_T)
    if (t < SCB) s[t] = h[t];
    __syncthreads();
    for (int off = 1; off < SCB; off <<= 1) {
        int a = (t < SCB && t >= off) ? s[t - off] : 0;
        __syncthreads();
        if (t < SCB) s[t] += a;
        __syncthreads();
    }
    if (t < SCB) {
        int c = h[t];
        int ex = s[t] - c;
        int gp = c ? atomicAdd(&gcursor[t], c) : 0;
        delta[t] = gp - ex;
        h[t] = ex;  // local insert cursor
    }
    __syncthreads();
    for (int i = t; i < cnt; i += SC_T) {
        int d = dst[base + i];
        int b = d >> NPB_SHIFT;
        int pos = atomicAdd(&h[b], 1);
        lout[pos] = ((d & (NPB - 1)) << SRC_BITS) | src[base + i];
    }
    __syncthreads();
    for (int i = t; i < cnt; i += SC_T) {
        // smallest b with s[b] > i
        int lo = 0, hi = SCB - 1;
        while (lo < hi) {
            int mid = (lo + hi) >> 1;
            if (s[mid] > i) hi = mid;
            else lo = mid + 1;
        }
        packed[delta[lo] + i] = lout[i];
    }
}

__global__ __launch_bounds__(CSR_T) void csr_build(
    const int* __restrict__ packed, const int* __restrict__ gcursor,
    int* __restrict__ deg, int* __restrict__ offs,
    int* __restrict__ csr_src, int* __restrict__ hist, int N) {
    __shared__ int lout[CAP_B];
    __shared__ int ldeg[NPB];
    __shared__ int lofs[NPB];
    __shared__ int lhist[DBINS];
    int b = blockIdx.x;
    int t = threadIdx.x;
    int e0 = b * CAP_B;
    int cnt = gcursor[b] - e0;
    if (t < NPB) ldeg[t] = 0;
    if (t < DBINS) lhist[t] = 0;
    __syncthreads();
    for (int i = t; i < cnt; i += CSR_T)
        atomicAdd(&ldeg[packed[e0 + i] >> SRC_BITS], 1);
    __syncthreads();
    int v = (t < NPB) ? ldeg[t] : 0;
    if (t < NPB) lofs[t] = v;
    if (t < NPB) atomicAdd(&lhist[v < DBINS ? v : DBINS - 1], 1);
    __syncthreads();
    for (int off = 1; off < NPB; off <<= 1) {
        int u = (t < NPB && t >= off) ? lofs[t - off] : 0;
        __syncthreads();
        if (t < NPB) lofs[t] += u;
        __syncthreads();
    }
    if (t < NPB) {
        int ex = lofs[t] - v;
        int node = (b << NPB_SHIFT) + t;
        if (node < N) {
            deg[node] = v;
            offs[node] = e0 + ex;
        }
        lofs[t] = ex;  // reuse as cursor
    }
    __syncthreads();
    for (int i = t; i < cnt; i += CSR_T) {
        int p = packed[e0 + i];
        int pos = atomicAdd(&lofs[p >> SRC_BITS], 1);
        lout[pos] = p & SRC_MASK;
    }
    __syncthreads();
    for (int i = t; i < cnt; i += CSR_T)
        csr_src[e0 + i] = lout[i];
    // per-block degree histogram -> global (for degree sort)
    if (t < DBINS && lhist[t]) atomicAdd(&hist[t], lhist[t]);
}

// ---------------- degree sort: exclusive scan of 256 bins + stable-ish scatter -
__global__ void deg_scan(const int* __restrict__ hist, int* __restrict__ cursor) {
    __shared__ int s[DBINS];
    int t = threadIdx.x;
    int h = hist[t];
    s[t] = h;
    __syncthreads();
    for (int off = 1; off < DBINS; off <<= 1) {
        int a = (t >= off) ? s[t - off] : 0;
        __syncthreads();
        s[t] += a;
        __syncthreads();
    }
    cursor[t] = s[t] - h;  // exclusive prefix
}

__global__ void deg_scatter(const int* __restrict__ deg, const int* __restrict__ offs,
                            int* __restrict__ cursor, int* __restrict__ perm,
                            int* __restrict__ sdeg, int* __restrict__ soffs, int N) {
    __shared__ int lh[DBINS];
    __shared__ int lb[DBINS];
    int t = threadIdx.x;
    if (t < DBINS) lh[t] = 0;
    __syncthreads();
    int i = blockIdx.x * blockDim.x + t;
    int bin = 0, r = 0, dv = 0;
    if (i < N) {
        dv = deg[i];
        bin = dv < DBINS ? dv : DBINS - 1;
        r = atomicAdd(&lh[bin], 1);
    }
    __syncthreads();
    if (t < DBINS && lh[t]) lb[t] = atomicAdd(&cursor[t], lh[t]);
    __syncthreads();
    if (i < N) {
        int p = lb[bin] + r;
        perm[p] = i;
        sdeg[p] = dv;
        soffs[p] = offs[i];
    }
}

// ---------------- conv1: 2 lanes/node, 16 B gathers, degree-sorted schedule ----
__global__ __launch_bounds__(256) void agnn_conv1(
    const int* __restrict__ rec1,
    const int* __restrict__ soffs, const int* __restrict__ sdeg,
    const int* __restrict__ csr, const int* __restrict__ perm,
    const float* __restrict__ beta_p,
    int* __restrict__ rec2, int N) {
    int tid = blockIdx.x * blockDim.x + threadIdx.x;
    int slot = tid >> 1;
    int q = tid & 1;
    if (slot >= N) return;
    int node = perm[slot];
    float beta = beta_p[0];
    const int4* rp = (const int4*)rec1;

    QRowU2 rdu;
    rdu.v = rp[2 * node + q];
    float xd[8];
#pragma unroll
    for (int k = 0; k < 8; ++k) xd[k] = (float)rdu.h[k];

    float ssd = 0.f;
#pragma unroll
    for (int k = 0; k < 8; ++k) ssd = fmaf(xd[k], xd[k], ssd);
    ssd += __shfl_xor(ssd, 1);
    float invsd = rsqrtf(fmaxf(ssd, SSEPS));

    // self edge: cos = ssd*invsd^2 (1, or 0 for a zero row)
    float e0 = __expf(beta * ssd * invsd * invsd);
    float denom = e0;
    float acc[8];
#pragma unroll
    for (int k = 0; k < 8; ++k) acc[k] = e0 * xd[k];

    int start = soffs[slot], cnt = sdeg[slot];
    int i = 0;
    for (; i + 8 <= cnt; i += 8) {
        int j[8];
        QRowU2 r[8];
#pragma unroll
        for (int u = 0; u < 8; ++u) j[u] = __builtin_nontemporal_load(&csr[start + i + u]);
#pragma unroll
        for (int u = 0; u < 8; ++u) r[u].v = rp[2 * j[u] + q];
#pragma unroll
        for (int u = 0; u < 8; ++u) {
            float d = 0.f, ss = 0.f;
            float hs[8];
#pragma unroll
            for (int k = 0; k < 8; ++k) {
                hs[k] = (float)r[u].h[k];
                d = fmaf(xd[k], hs[k], d);
                ss = fmaf(hs[k], hs[k], ss);
            }
            d += __shfl_xor(d, 1);
            ss += __shfl_xor(ss, 1);
            float ee = __expf(beta * d * invsd * rsqrtf(fmaxf(ss, SSEPS)));
            denom += ee;
#pragma unroll
            for (int k = 0; k < 8; ++k) acc[k] = fmaf(ee, hs[k], acc[k]);
        }
    }
    for (; i < cnt; ++i) {
        int j = __builtin_nontemporal_load(&csr[start + i]);
        QRowU2 r;
        r.v = rp[2 * j + q];
        float d = 0.f, ss = 0.f;
        float hs[8];
#pragma unroll
        for (int k = 0; k < 8; ++k) {
            hs[k] = (float)r.h[k];
            d = fmaf(xd[k], hs[k], d);
            ss = fmaf(hs[k], hs[k], ss);
        }
        d += __shfl_xor(d, 1);
        ss += __shfl_xor(ss, 1);
        float ee = __expf(beta * d * invsd * rsqrtf(fmaxf(ss, SSEPS)));
        denom += ee;
#pragma unroll
        for (int k = 0; k < 8; ++k) acc[k] = fmaf(ee, hs[k], acc[k]);
    }

    // epilogue: out1 = acc/denom, written as raw fp16 row
    float inv = 1.f / denom;
    QRowU2 w;
#pragma unroll
    for (int k = 0; k < 8; ++k) w.h[k] = (_Float16)(acc[k] * inv);
    ((int4*)rec2)[2 * node + q] = w.v;
}

// ---------------- conv2: 2 lanes/node, payload = v.row computed in-register ---
__global__ __launch_bounds__(256) void agnn_conv2(
    const int* __restrict__ rec2,
    const int* __restrict__ soffs, const int* __restrict__ sdeg,
    const int* __restrict__ csr, const int* __restrict__ perm,
    const float* __restrict__ beta_p,
    const float* __restrict__ vbuf,
    float* __restrict__ rbuf, int N) {
    int tid = blockIdx.x * blockDim.x + threadIdx.x;
    int slot = tid >> 1;
    int q = tid & 1;
    if (slot >= N) return;
    int node = perm[slot];
    float beta = beta_p[0];
    const int4* rp = (const int4*)rec2;

    float vq[8];
#pragma unroll
    for (int k = 0; k < 8; ++k) vq[k] = vbuf[8 * q + k];

    QRowU2 rdu;
    rdu.v = rp[2 * node + q];
    float xd[8];
#pragma unroll
    for (int k = 0; k < 8; ++k) xd[k] = (float)rdu.h[k];

    float ssd = 0.f, pd = 0.f;
#pragma unroll
    for (int k = 0; k < 8; ++k) {
        ssd = fmaf(xd[k], xd[k], ssd);
        pd = fmaf(vq[k], xd[k], pd);
    }
    ssd += __shfl_xor(ssd, 1);
    pd += __shfl_xor(pd, 1);
    float invsd = rsqrtf(fmaxf(ssd, SSEPS));

    float e0 = __expf(beta * ssd * invsd * invsd);
    float denom = e0;
    float acc = e0 * pd;

    int start = soffs[slot], cnt = sdeg[slot];
    int i = 0;
    for (; i + 8 <= cnt; i += 8) {
        int j[8];
        QRowU2 r[8];
#pragma unroll
        for (int u = 0; u < 8; ++u) j[u] = __builtin_nontemporal_load(&csr[start + i + u]);
#pragma unroll
        for (int u = 0; u < 8; ++u) r[u].v = rp[2 * j[u] + q];
#pragma unroll
        for (int u = 0; u < 8; ++u) {
            float d = 0.f, ss = 0.f, pv = 0.f;
#pragma unroll
            for (int k = 0; k < 8; ++k) {
                float hs = (float)r[u].h[k];
                d = fmaf(xd[k], hs, d);
                ss = fmaf(hs, hs, ss);
                pv = fmaf(vq[k], hs, pv);
            }
            d += __shfl_xor(d, 1);
            ss += __shfl_xor(ss, 1);
            pv += __shfl_xor(pv, 1);
            float ee = __expf(beta * d * invsd * rsqrtf(fmaxf(ss, SSEPS)));
            denom += ee;
            acc = fmaf(ee, pv, acc);
        }
    }
    for (; i < cnt; ++i) {
        int j = __builtin_nontemporal_load(&csr[start + i]);
        QRowU2 r;
        r.v = rp[2 * j + q];
        float d = 0.f, ss = 0.f, pv = 0.f;
#pragma unroll
        for (int k = 0; k < 8; ++k) {
            float hs = (float)r.h[k];
            d = fmaf(xd[k], hs, d);
            ss = fmaf(hs, hs, ss);
            pv = fmaf(vq[k], hs, pv);
        }
        d += __shfl_xor(d, 1);
        ss += __shfl_xor(ss, 1);
        pv += __shfl_xor(pv, 1);
        float ee = __expf(beta * d * invsd * rsqrtf(fmaxf(ss, SSEPS)));
        denom += ee;
        acc = fmaf(ee, pv, acc);
    }
    if (q == 0) rbuf[node] = acc / denom;
}

// ---------------- pooling: sorted batch -> per-thread 8-node run aggregation --
__global__ void pool_kernel(const float* __restrict__ r, const int* __restrict__ batch,
                            const float* __restrict__ vbuf, float* __restrict__ out,
                            int N) {
    int base = (blockIdx.x * blockDim.x + threadIdx.x) * 8;
    if (base >= N) return;
    float c0 = vbuf[16];
    int lim = base + 8;
    if (lim > N) lim = N;
    float run = 0.f;
    int g = -1;
    for (int i = base; i < lim; ++i) {
        int gi = batch[i];
        if (gi != g) {
            if (g >= 0) atomicAdd(&out[g], run);
            g = gi;
            run = 0.f;
        }
        run += r[i] + c0;
    }
    if (g >= 0) atomicAdd(&out[g], run);
}

// ---------------- launcher ----------------

extern "C" void kernel_launch(void* const* d_in, const int* in_sizes, int n_in,
                              void* d_out, int out_size, void* d_ws, size_t ws_size,
                              hipStream_t stream) {
    const float* x = (const float*)d_in[0];
    const int* edge_index = (const int*)d_in[1];
    const int* batch = (const int*)d_in[2];
    const float* lin1_w = (const float*)d_in[4];
    const float* lin1_b = (const float*)d_in[5];
    const float* beta1 = (const float*)d_in[6];
    const float* beta2 = (const float*)d_in[7];
    const float* lin2_w = (const float*)d_in[8];
    const float* lin2_b = (const float*)d_in[9];
    const float* gather_w = (const float*)d_in[10];
    const float* gather_b = (const float*)d_in[11];
    float* out = (float*)d_out;

    const int N = in_sizes[2];
    const int E = in_sizes[1] / 2;
    const int D = in_sizes[0] / N;  // 75
    const int G = out_size;

    const int* src = edge_index;
    const int* dst = edge_index + E;

    // workspace carve (4-byte words); 32 B node records, padded bucket regions.
    float* w = (float*)d_ws;
    int* rec1 = (int*)w;                 w += (size_t)N * 8;   // 4 MB
    int* rec2 = (int*)w;                 w += (size_t)N * 8;   // 4 MB
    float* rbuf = w;                     w += N;
    float* vbuf = w;                     w += 32;
    int* deg = (int*)w;                  w += N;
    int* offs = (int*)w;                 w += N;
    int* packed = (int*)w;               w += (size_t)NB * CAP_B;
    int* csr_src = (int*)w;              w += (size_t)NB * CAP_B;
    int* gcursor = (int*)w;              w += NB;
    int* perm = (int*)w;                 w += N;
    int* sdeg = (int*)w;                 w += N;
    int* soffs = (int*)w;                w += N;
    int* hist = (int*)w;                 w += DBINS;
    int* cursor = (int*)w;               w += DBINS;

    const int B = 256;
    dim3 gridNode16((N + (B / 16) - 1) / (B / 16));
    dim3 gridNode2((2 * N + B - 1) / B);

    // ---- CSR build (2 passes over edges, padded bucket regions) ----
    init_gcursor<<<dim3(1), NB, 0, stream>>>(gcursor, hist);
    bucket_scatter<<<dim3((E + SC_EDGES - 1) / SC_EDGES), SC_T, 0, stream>>>(
        src, dst, E, gcursor, packed);
    csr_build<<<dim3(NB), CSR_T, 0, stream>>>(packed, gcursor, deg, offs, csr_src,
                                              hist, N);

    // ---- degree-sorted node schedule (numerics-invariant) ----
    deg_scan<<<dim3(1), DBINS, 0, stream>>>(hist, cursor);
    deg_scatter<<<dim3((N + B - 1) / B), B, 0, stream>>>(deg, offs, cursor, perm,
                                                         sdeg, soffs, N);

    // ---- features ----
    lin1_relu<<<gridNode16, B, 0, stream>>>(x, lin1_w, lin1_b, rec1, N, D);
    compute_v<<<dim3(1), 64, 0, stream>>>(lin2_w, lin2_b, gather_w, vbuf);

    agnn_conv1<<<gridNode2, B, 0, stream>>>(rec1, soffs, sdeg, csr_src, perm,
                                            beta1, rec2, N);
    agnn_conv2<<<gridNode2, B, 0, stream>>>(rec2, soffs, sdeg, csr_src, perm,
                                            beta2, vbuf, rbuf, N);

    init_out<<<dim3((G + B - 1) / B), B, 0, stream>>>(out, gather_b, G);
    pool_kernel<<<dim3((N / 8 + B - 1) / B), B, 0, stream>>>(rbuf, batch, vbuf, out, N);
}

// Round 2
// 282.182 us; speedup vs baseline: 1.1295x; 1.1295x over previous
//
#include <hip/hip_runtime.h>
#include <hip/hip_bf16.h>
#include <hip/hip_fp16.h>
#include <math.h>

#define SSEPS 1e-24f
#define NPB 256           // nodes per bucket
#define NPB_SHIFT 8
#define SRC_BITS 17       // N = 131072 = 2^17
#define SRC_MASK ((1 << SRC_BITS) - 1)
#define NB 512            // buckets (N / NPB)
#define CAP_B 8832        // padded per-bucket region (mean 8192 + 7 sigma)
#define SC_EDGES 4096     // edges per scatter block
#define SCB 512           // bucket count in scatter LDS
#define MG_T 512          // mega kernel threads
#define MG_SCAT 1024      // scatter blocks (E / SC_EDGES)
#define MG_LIN 4096       // lin1 blocks (N / 32)
#define CSR_T 512         // csr_build threads

union QRowU2 { int4 v; _Float16 h[8]; };

// Node record: 32 B = 8 ints = fp16[16] RAW feature row. 2 lanes/node, each
// lane gathers one int4 (16 B); norms/projections recomputed in-register.

// ---------------- mega kernel: scatter | lin1 | compute_v | init_out ----------
// All four phases are mutually independent; fusing hides lin1 under the
// scatter's memory latency and saves 3 launches.
__global__ __launch_bounds__(MG_T) void mega1(
    const int* __restrict__ src, const int* __restrict__ dst, int E,
    int* __restrict__ gcursor, int* __restrict__ packed,
    const float* __restrict__ x, const float* __restrict__ W1,
    const float* __restrict__ b1, int* __restrict__ rec1, int N, int D,
    const float* __restrict__ l2w, const float* __restrict__ l2b,
    const float* __restrict__ gw, float* __restrict__ vbuf,
    float* __restrict__ out, const float* __restrict__ gb, int G) {
    __shared__ int sh[2 * SC_EDGES + 3 * SCB];  // 38.9 KB
    int bid = blockIdx.x;
    int t = threadIdx.x;

    if (bid < MG_SCAT) {
        // ---- bucket scatter: edges [bid*SC_EDGES, +SC_EDGES) -> packed ----
        int* lout = sh;                    // staged edge payloads
        int* loutd = sh + SC_EDGES;        // staged global destinations
        int* h = sh + 2 * SC_EDGES;        // histogram / insert cursor
        int* s = h + SCB;                  // inclusive scan
        int* delta = s + SCB;              // global base - local exclusive
        int base = bid * SC_EDGES;
        int cnt = E - base;
        if (cnt > SC_EDGES) cnt = SC_EDGES;

        h[t] = 0;
        __syncthreads();
        for (int i = t; i < cnt; i += MG_T)
            atomicAdd(&h[dst[base + i] >> NPB_SHIFT], 1);
        __syncthreads();
        s[t] = h[t];
        __syncthreads();
        for (int off = 1; off < SCB; off <<= 1) {
            int a = (t >= off) ? s[t - off] : 0;
            __syncthreads();
            s[t] += a;
            __syncthreads();
        }
        {
            int c = h[t];
            int ex = s[t] - c;
            int gp = c ? atomicAdd(&gcursor[t], c) : 0;   // gcursor = count
            delta[t] = (t * CAP_B + gp) - ex;
            h[t] = ex;  // local insert cursor
        }
        __syncthreads();
        for (int i = t; i < cnt; i += MG_T) {
            int d = dst[base + i];
            int b = d >> NPB_SHIFT;
            int pos = atomicAdd(&h[b], 1);
            lout[pos] = ((d & (NPB - 1)) << SRC_BITS) | src[base + i];
            loutd[pos] = delta[b] + pos;
        }
        __syncthreads();
        for (int i = t; i < cnt; i += MG_T)
            packed[loutd[i]] = lout[i];
    } else if (bid < MG_SCAT + MG_LIN) {
        // ---- lin1 + relu -> raw fp16 rows, 32 nodes/block, 16 thr/node ----
        float* Ws = (float*)sh;
        float* Bs = Ws + 16 * 75;
        for (int i = t; i < 16 * D; i += MG_T) Ws[i] = W1[i];
        if (t < 16) Bs[t] = b1[t];
        __syncthreads();
        int node = (bid - MG_SCAT) * (MG_T >> 4) + (t >> 4);
        int c = t & 15;
        if (node >= N) return;
        const float* xr = x + (size_t)node * D;
        float acc = Bs[c];
        for (int k = 0; k < D; ++k) acc = fmaf(xr[k], Ws[c * D + k], acc);
        float hv = fmaxf(acc, 0.f);
        float hn = __shfl_xor(hv, 1);
        if (!(c & 1)) {
            union { _Float16 hh[2]; int i; } u;
            u.hh[0] = (_Float16)hv;
            u.hh[1] = (_Float16)hn;
            rec1[8 * node + (c >> 1)] = u.i;
        }
    } else if (bid == MG_SCAT + MG_LIN) {
        // ---- compute_v: v[c] = sum_j gw[j]*l2w[j][c]; v[16] = gw.l2b ----
        if (t < 16) {
            float a = 0.f;
            for (int j = 0; j < 64; ++j) a = fmaf(gw[j], l2w[j * 16 + t], a);
            vbuf[t] = a;
        } else if (t == 16) {
            float a = 0.f;
            for (int j = 0; j < 64; ++j) a = fmaf(gw[j], l2b[j], a);
            vbuf[16] = a;
        }
    } else {
        // ---- init_out ----
        int g = (bid - (MG_SCAT + MG_LIN + 1)) * MG_T + t;
        if (g < G) out[g] = gb[0];
    }
}

// ---------------- csr_build: per-bucket sort into node-grouped lists ----------
__global__ __launch_bounds__(CSR_T) void csr_build(
    const int* __restrict__ packed, const int* __restrict__ gcursor,
    int* __restrict__ deg, int* __restrict__ offs,
    int* __restrict__ csr_src, int N) {
    __shared__ int lout[CAP_B];
    __shared__ int ldeg[NPB];
    __shared__ int lofs[NPB];
    int b = blockIdx.x;
    int t = threadIdx.x;
    int e0 = b * CAP_B;
    int cnt = gcursor[b];   // gcursor holds per-bucket edge count
    if (t < NPB) ldeg[t] = 0;
    __syncthreads();
    for (int i = t; i < cnt; i += CSR_T)
        atomicAdd(&ldeg[packed[e0 + i] >> SRC_BITS], 1);
    __syncthreads();
    int v = (t < NPB) ? ldeg[t] : 0;
    if (t < NPB) lofs[t] = v;
    __syncthreads();
    for (int off = 1; off < NPB; off <<= 1) {
        int u = (t < NPB && t >= off) ? lofs[t - off] : 0;
        __syncthreads();
        if (t < NPB) lofs[t] += u;
        __syncthreads();
    }
    if (t < NPB) {
        int ex = lofs[t] - v;
        int node = (b << NPB_SHIFT) + t;
        if (node < N) {
            deg[node] = v;
            offs[node] = e0 + ex;
        }
        lofs[t] = ex;  // reuse as cursor
    }
    __syncthreads();
    for (int i = t; i < cnt; i += CSR_T) {
        int p = packed[e0 + i];
        int pos = atomicAdd(&lofs[p >> SRC_BITS], 1);
        lout[pos] = p & SRC_MASK;
    }
    __syncthreads();
    for (int i = t; i < cnt; i += CSR_T)
        csr_src[e0 + i] = lout[i];
}

// ---------------- conv1: 2 lanes/node, 16 B gathers ----------
__global__ __launch_bounds__(256) void agnn_conv1(
    const int* __restrict__ rec1,
    const int* __restrict__ offs, const int* __restrict__ deg,
    const int* __restrict__ csr, const float* __restrict__ beta_p,
    int* __restrict__ rec2, int N) {
    int tid = blockIdx.x * blockDim.x + threadIdx.x;
    int node = tid >> 1;
    int q = tid & 1;
    if (node >= N) return;
    float beta = beta_p[0];
    const int4* rp = (const int4*)rec1;

    QRowU2 rdu;
    rdu.v = rp[2 * node + q];
    float xd[8];
#pragma unroll
    for (int k = 0; k < 8; ++k) xd[k] = (float)rdu.h[k];

    float ssd = 0.f;
#pragma unroll
    for (int k = 0; k < 8; ++k) ssd = fmaf(xd[k], xd[k], ssd);
    ssd += __shfl_xor(ssd, 1);
    float invsd = rsqrtf(fmaxf(ssd, SSEPS));

    // self edge: cos = ssd*invsd^2 (1, or 0 for a zero row)
    float e0 = __expf(beta * ssd * invsd * invsd);
    float denom = e0;
    float acc[8];
#pragma unroll
    for (int k = 0; k < 8; ++k) acc[k] = e0 * xd[k];

    int start = offs[node], cnt = deg[node];
    int i = 0;
    for (; i + 8 <= cnt; i += 8) {
        int j[8];
        QRowU2 r[8];
#pragma unroll
        for (int u = 0; u < 8; ++u) j[u] = __builtin_nontemporal_load(&csr[start + i + u]);
#pragma unroll
        for (int u = 0; u < 8; ++u) r[u].v = rp[2 * j[u] + q];
#pragma unroll
        for (int u = 0; u < 8; ++u) {
            float d = 0.f, ss = 0.f;
            float hs[8];
#pragma unroll
            for (int k = 0; k < 8; ++k) {
                hs[k] = (float)r[u].h[k];
                d = fmaf(xd[k], hs[k], d);
                ss = fmaf(hs[k], hs[k], ss);
            }
            d += __shfl_xor(d, 1);
            ss += __shfl_xor(ss, 1);
            float ee = __expf(beta * d * invsd * rsqrtf(fmaxf(ss, SSEPS)));
            denom += ee;
#pragma unroll
            for (int k = 0; k < 8; ++k) acc[k] = fmaf(ee, hs[k], acc[k]);
        }
    }
    for (; i < cnt; ++i) {
        int j = __builtin_nontemporal_load(&csr[start + i]);
        QRowU2 r;
        r.v = rp[2 * j + q];
        float d = 0.f, ss = 0.f;
        float hs[8];
#pragma unroll
        for (int k = 0; k < 8; ++k) {
            hs[k] = (float)r.h[k];
            d = fmaf(xd[k], hs[k], d);
            ss = fmaf(hs[k], hs[k], ss);
        }
        d += __shfl_xor(d, 1);
        ss += __shfl_xor(ss, 1);
        float ee = __expf(beta * d * invsd * rsqrtf(fmaxf(ss, SSEPS)));
        denom += ee;
#pragma unroll
        for (int k = 0; k < 8; ++k) acc[k] = fmaf(ee, hs[k], acc[k]);
    }

    // epilogue: out1 = acc/denom, written as raw fp16 row
    float inv = 1.f / denom;
    QRowU2 w;
#pragma unroll
    for (int k = 0; k < 8; ++k) w.h[k] = (_Float16)(acc[k] * inv);
    ((int4*)rec2)[2 * node + q] = w.v;
}

// ---------------- conv2: 2 lanes/node, payload = v.row computed in-register ---
__global__ __launch_bounds__(256) void agnn_conv2(
    const int* __restrict__ rec2,
    const int* __restrict__ offs, const int* __restrict__ deg,
    const int* __restrict__ csr, const float* __restrict__ beta_p,
    const float* __restrict__ vbuf,
    float* __restrict__ rbuf, int N) {
    int tid = blockIdx.x * blockDim.x + threadIdx.x;
    int node = tid >> 1;
    int q = tid & 1;
    if (node >= N) return;
    float beta = beta_p[0];
    const int4* rp = (const int4*)rec2;

    float vq[8];
#pragma unroll
    for (int k = 0; k < 8; ++k) vq[k] = vbuf[8 * q + k];

    QRowU2 rdu;
    rdu.v = rp[2 * node + q];
    float xd[8];
#pragma unroll
    for (int k = 0; k < 8; ++k) xd[k] = (float)rdu.h[k];

    float ssd = 0.f, pd = 0.f;
#pragma unroll
    for (int k = 0; k < 8; ++k) {
        ssd = fmaf(xd[k], xd[k], ssd);
        pd = fmaf(vq[k], xd[k], pd);
    }
    ssd += __shfl_xor(ssd, 1);
    pd += __shfl_xor(pd, 1);
    float invsd = rsqrtf(fmaxf(ssd, SSEPS));

    float e0 = __expf(beta * ssd * invsd * invsd);
    float denom = e0;
    float acc = e0 * pd;

    int start = offs[node], cnt = deg[node];
    int i = 0;
    for (; i + 8 <= cnt; i += 8) {
        int j[8];
        QRowU2 r[8];
#pragma unroll
        for (int u = 0; u < 8; ++u) j[u] = __builtin_nontemporal_load(&csr[start + i + u]);
#pragma unroll
        for (int u = 0; u < 8; ++u) r[u].v = rp[2 * j[u] + q];
#pragma unroll
        for (int u = 0; u < 8; ++u) {
            float d = 0.f, ss = 0.f, pv = 0.f;
#pragma unroll
            for (int k = 0; k < 8; ++k) {
                float hs = (float)r[u].h[k];
                d = fmaf(xd[k], hs, d);
                ss = fmaf(hs, hs, ss);
                pv = fmaf(vq[k], hs, pv);
            }
            d += __shfl_xor(d, 1);
            ss += __shfl_xor(ss, 1);
            pv += __shfl_xor(pv, 1);
            float ee = __expf(beta * d * invsd * rsqrtf(fmaxf(ss, SSEPS)));
            denom += ee;
            acc = fmaf(ee, pv, acc);
        }
    }
    for (; i < cnt; ++i) {
        int j = __builtin_nontemporal_load(&csr[start + i]);
        QRowU2 r;
        r.v = rp[2 * j + q];
        float d = 0.f, ss = 0.f, pv = 0.f;
#pragma unroll
        for (int k = 0; k < 8; ++k) {
            float hs = (float)r.h[k];
            d = fmaf(xd[k], hs, d);
            ss = fmaf(hs, hs, ss);
            pv = fmaf(vq[k], hs, pv);
        }
        d += __shfl_xor(d, 1);
        ss += __shfl_xor(ss, 1);
        pv += __shfl_xor(pv, 1);
        float ee = __expf(beta * d * invsd * rsqrtf(fmaxf(ss, SSEPS)));
        denom += ee;
        acc = fmaf(ee, pv, acc);
    }
    if (q == 0) rbuf[node] = acc / denom;
}

// ---------------- pooling: sorted batch -> per-thread 8-node run aggregation --
__global__ void pool_kernel(const float* __restrict__ r, const int* __restrict__ batch,
                            const float* __restrict__ vbuf, float* __restrict__ out,
                            int N) {
    int base = (blockIdx.x * blockDim.x + threadIdx.x) * 8;
    if (base >= N) return;
    float c0 = vbuf[16];
    int lim = base + 8;
    if (lim > N) lim = N;
    float run = 0.f;
    int g = -1;
    for (int i = base; i < lim; ++i) {
        int gi = batch[i];
        if (gi != g) {
            if (g >= 0) atomicAdd(&out[g], run);
            g = gi;
            run = 0.f;
        }
        run += r[i] + c0;
    }
    if (g >= 0) atomicAdd(&out[g], run);
}

// ---------------- launcher ----------------

extern "C" void kernel_launch(void* const* d_in, const int* in_sizes, int n_in,
                              void* d_out, int out_size, void* d_ws, size_t ws_size,
                              hipStream_t stream) {
    const float* x = (const float*)d_in[0];
    const int* edge_index = (const int*)d_in[1];
    const int* batch = (const int*)d_in[2];
    const float* lin1_w = (const float*)d_in[4];
    const float* lin1_b = (const float*)d_in[5];
    const float* beta1 = (const float*)d_in[6];
    const float* beta2 = (const float*)d_in[7];
    const float* lin2_w = (const float*)d_in[8];
    const float* lin2_b = (const float*)d_in[9];
    const float* gather_w = (const float*)d_in[10];
    const float* gather_b = (const float*)d_in[11];
    float* out = (float*)d_out;

    const int N = in_sizes[2];
    const int E = in_sizes[1] / 2;
    const int D = in_sizes[0] / N;  // 75
    const int G = out_size;

    const int* src = edge_index;
    const int* dst = edge_index + E;

    // workspace carve (4-byte words); 32 B node records, padded bucket regions.
    float* w = (float*)d_ws;
    int* rec1 = (int*)w;                 w += (size_t)N * 8;   // 4 MB
    int* rec2 = (int*)w;                 w += (size_t)N * 8;   // 4 MB
    float* rbuf = w;                     w += N;
    float* vbuf = w;                     w += 32;
    int* deg = (int*)w;                  w += N;
    int* offs = (int*)w;                 w += N;
    int* packed = (int*)w;               w += (size_t)NB * CAP_B;
    int* csr_src = (int*)w;              w += (size_t)NB * CAP_B;
    int* gcursor = (int*)w;              w += NB;

    const int B = 256;
    dim3 gridNode2((2 * N + B - 1) / B);

    // gcursor holds per-bucket counts now; zero it via memset (capturable).
    hipMemsetAsync(gcursor, 0, NB * sizeof(int), stream);

    // ---- fused: bucket_scatter | lin1+relu | compute_v | init_out ----
    int nScat = (E + SC_EDGES - 1) / SC_EDGES;          // 1024
    int nLin = (N + (MG_T / 16) - 1) / (MG_T / 16);     // 4096
    int nOut = (G + MG_T - 1) / MG_T;                   // 4
    dim3 megaGrid(nScat + nLin + 1 + nOut);
    mega1<<<megaGrid, MG_T, 0, stream>>>(src, dst, E, gcursor, packed,
                                         x, lin1_w, lin1_b, rec1, N, D,
                                         lin2_w, lin2_b, gather_w, vbuf,
                                         out, gather_b, G);

    csr_build<<<dim3(NB), CSR_T, 0, stream>>>(packed, gcursor, deg, offs,
                                              csr_src, N);

    agnn_conv1<<<gridNode2, B, 0, stream>>>(rec1, offs, deg, csr_src,
                                            beta1, rec2, N);
    agnn_conv2<<<gridNode2, B, 0, stream>>>(rec2, offs, deg, csr_src,
                                            beta2, vbuf, rbuf, N);

    pool_kernel<<<dim3((N / 8 + B - 1) / B), B, 0, stream>>>(rbuf, batch, vbuf, out, N);
}